// Round 1
// baseline (380.869 us; speedup 1.0000x reference)
//
#include <hip/hip_runtime.h>

#define BB 512
#define TT 2048

// ---------- fast math helpers ----------
__device__ __forceinline__ float fexp2(float x){ return __builtin_amdgcn_exp2f(x); }
__device__ __forceinline__ float frcp(float x){ return __builtin_amdgcn_rcpf(x); }

#define QB(v, ctrl) __int_as_float(__builtin_amdgcn_mov_dpp(__float_as_int(v), (ctrl), 0xF, 0xF, true))
#define RL(v, l)    __builtin_amdgcn_readlane((v), (l))

// ---------- fused recurrence: input projection computed in-wave, off critical path ----------
// 1 chain/wave; lane 4j+q = gate q of unit j; lane 52 rides along computing the FC output
// using the SAME instruction stream (its w = -log2e*fc_w, its bias = -log2e*fc_b, wx = 0).
// Input projection sx = kq*(b_ih+b_hh) + kq*Wih_row·x_t is independent of h, so its
// 13 readlane + 13 FMA per step sink into the ~158 stall cycles of the serial chain.
__global__ __launch_bounds__(64, 1) void k_rec_f(
    const float* __restrict__ x,
    const float* __restrict__ Wih,
    const float* __restrict__ Whh,
    const float* __restrict__ bih,
    const float* __restrict__ bhh,
    const float* __restrict__ fcw,
    const float* __restrict__ fcb,
    float* __restrict__ out)
{
  const int lane = threadIdx.x;
  const int b    = blockIdx.x;
  const int q    = lane & 3;
  const int j    = lane >> 2;             // 0..15 (13..15 padding)
  const int jc   = (j < 13) ? j : 12;
  const bool fcl = (lane == 52);
  const int e    = fcl ? 0 : q*13 + jc;   // weight row (lane 52 reads row 0, scaled by 0)

  const float kq = (q==2) ? -2.8853900817779268f : -1.4426950408889634f;
  const float gm = (q==2) ? -5.7707801635558536f : 1.f;
  const float ga = (q==2) ?  2.8853900817779268f : 0.f;
  const float fcbias = -1.4426950408889634f * fcb[0];

  // recurrent weights: Whh row scaled by kq; lane 52 takes -log2e*fc_w (its q==0 -> kq=-log2e)
  const float* wsrc = fcl ? fcw : (Whh + e*13);
  const float  kx   = fcl ? 0.f : kq;

  float w[13], wx[13];
  #pragma unroll
  for (int k=0;k<13;k++) w[k]  = wsrc[k]*kq;
  #pragma unroll
  for (int k=0;k<13;k++) wx[k] = Wih[e*13+k]*kx;

  const float biass = fcl ? fcbias : (bih[e]+bhh[e])*kq;

  // coalesced x staging: group of 8 steps = 104 floats; lanes 0..51 hold float2 each.
  const float* xb = x + (size_t)b*(TT*13);
  const int ll = (lane < 52) ? lane : 51;

  float2 xcur = ((const float2*)(xb      ))[ll];   // group 0
  float2 xnxt = ((const float2*)(xb + 104))[ll];   // group 1

  float h = 0.f, c_ = 0.f;                // c_ carries -2*log2e*c
  float hb0=0,hb1=0,hb2=0,hb3=0,hb4=0,hb5=0,hb6=0,hb7=0,hb8=0,hb9=0,hb10=0,hb11=0,hb12=0;

  float p0=0,p1=0,p2=0,p3=0,p4=0,p5=0,p6=0,p7=0;   // out ring (lane 52's values used)
  float* op = out + (size_t)b*TT;
  bool first = true;

#define CAPTURE(gv_, u_) do {                                                 \
    if ((u_)==1) p0=(gv_); else if ((u_)==2) p1=(gv_);                        \
    else if ((u_)==3) p2=(gv_); else if ((u_)==4) p3=(gv_);                   \
    else if ((u_)==5) p4=(gv_); else if ((u_)==6) p5=(gv_);                   \
    else if ((u_)==7) p6=(gv_);                                               \
    else { p7=(gv_);                                                          \
      if (!first){                                                            \
        if (lane == 52){                                                      \
          float4* o4 = (float4*)op;                                           \
          o4[0] = make_float4(p0,p1,p2,p3);                                   \
          o4[1] = make_float4(p4,p5,p6,p7);                                   \
        }                                                                     \
        op += 8;                                                              \
      }                                                                       \
      first = false;                                                          \
    }                                                                         \
  } while(0)

#define STEP(xv_, u_) do {                                                    \
    float dA = fmaf(w[0], hb0, (xv_));                                        \
    dA = fmaf(w[1], hb1, dA);                                                 \
    dA = fmaf(w[2], hb2, dA);                                                 \
    dA = fmaf(w[3], hb3, dA);                                                 \
    dA = fmaf(w[4], hb4, dA);                                                 \
    float dB = w[5]*hb5;                                                      \
    dB = fmaf(w[6], hb6, dB);                                                 \
    dB = fmaf(w[7], hb7, dB);                                                 \
    dB = fmaf(w[8], hb8, dB);                                                 \
    float dC = w[9]*hb9;                                                      \
    dC = fmaf(w[10], hb10, dC);                                               \
    dC = fmaf(w[11], hb11, dC);                                               \
    dC = fmaf(w[12], hb12, dC);                                               \
    float s  = (dB + dC) + dA;                                                \
    float r  = frcp(1.f + fexp2(s));                                          \
    float g  = fmaf(gm, r, ga);                                               \
    CAPTURE(g, u_);                                                           \
    float ggb = QB(g, 0xAA);                                                  \
    float gfb = QB(g, 0x55);                                                  \
    float gob = QB(g, 0xFF);                                                  \
    float go2 = gob + gob;                                                    \
    c_ = fmaf(gfb, c_, g*ggb);                                                \
    float r2 = frcp(1.f + fexp2(c_));                                         \
    h = fmaf(go2, r2, -gob);                                                  \
    int hv_ = __float_as_int(h);                                              \
    hb0  = __int_as_float(RL(hv_, 0));                                        \
    hb1  = __int_as_float(RL(hv_, 4));                                        \
    hb2  = __int_as_float(RL(hv_, 8));                                        \
    hb3  = __int_as_float(RL(hv_, 12));                                       \
    hb4  = __int_as_float(RL(hv_, 16));                                       \
    hb5  = __int_as_float(RL(hv_, 20));                                       \
    hb6  = __int_as_float(RL(hv_, 24));                                       \
    hb7  = __int_as_float(RL(hv_, 28));                                       \
    hb8  = __int_as_float(RL(hv_, 32));                                       \
    hb9  = __int_as_float(RL(hv_, 36));                                       \
    hb10 = __int_as_float(RL(hv_, 40));                                       \
    hb11 = __int_as_float(RL(hv_, 44));                                       \
    hb12 = __int_as_float(RL(hv_, 48));                                       \
  } while(0)

// sx = biass + wx·x_t, built from the group's coalesced registers via readlane.
// f = u*13+k in [0,104): lane f>>1 holds component f&1. All compile-time folds.
#define STEPX(u_) do {                                                        \
    float sx_ = biass;                                                        \
    _Pragma("unroll")                                                         \
    for (int k_ = 0; k_ < 13; ++k_){                                          \
      const int f_ = (u_)*13 + k_;                                            \
      float xe_ = (f_ & 1) ? xcur.y : xcur.x;                                 \
      sx_ = fmaf(wx[k_], __int_as_float(RL(__float_as_int(xe_), f_>>1)), sx_);\
    }                                                                         \
    STEP(sx_, u_);                                                            \
  } while(0)

  for (int g=0; g<256; ++g){
    // prefetch group g+2 (distance ~2 groups ≈ 4000 cycles; branchless clamp)
    const int gn = (g+2 < 256) ? (g+2) : 255;
    float2 xfut = ((const float2*)(xb + (size_t)gn*104))[ll];
    STEPX(0); STEPX(1); STEPX(2); STEPX(3);
    STEPX(4); STEPX(5); STEPX(6); STEPX(7);
    xcur = xnxt; xnxt = xfut;
  }

  // epilogue: out[2047] = sigmoid(fc_b + fc_w·h_2047); lane 52 stores p0..p6 + r
  {
    float s = fcbias;
    s = fmaf(w[0],  hb0,  s);
    s = fmaf(w[1],  hb1,  s);
    s = fmaf(w[2],  hb2,  s);
    s = fmaf(w[3],  hb3,  s);
    s = fmaf(w[4],  hb4,  s);
    s = fmaf(w[5],  hb5,  s);
    s = fmaf(w[6],  hb6,  s);
    s = fmaf(w[7],  hb7,  s);
    s = fmaf(w[8],  hb8,  s);
    s = fmaf(w[9],  hb9,  s);
    s = fmaf(w[10], hb10, s);
    s = fmaf(w[11], hb11, s);
    s = fmaf(w[12], hb12, s);
    float r = frcp(1.f + fexp2(s));
    if (lane == 52){
      float4* o4 = (float4*)op;           // op == out + b*TT + 2040 here
      o4[0] = make_float4(p0,p1,p2,p3);
      o4[1] = make_float4(p4,p5,p6,r);
    }
  }

#undef STEPX
#undef STEP
#undef CAPTURE
}

extern "C" void kernel_launch(void* const* d_in, const int* in_sizes, int n_in,
                              void* d_out, int out_size, void* d_ws, size_t ws_size,
                              hipStream_t stream)
{
  const float* x   = (const float*)d_in[0];
  const float* Wih = (const float*)d_in[1];
  const float* Whh = (const float*)d_in[2];
  const float* bih = (const float*)d_in[3];
  const float* bhh = (const float*)d_in[4];
  const float* fcw = (const float*)d_in[5];
  const float* fcb = (const float*)d_in[6];
  float* out = (float*)d_out;

  (void)d_ws; (void)ws_size;  // fully fused: no workspace, no precompute pass
  k_rec_f<<<dim3(BB), dim3(64), 0, stream>>>(x, Wih, Whh, bih, bhh, fcw, fcb, out);
}

// Round 2
// 365.427 us; speedup vs baseline: 1.0423x; 1.0423x over previous
//
#include <hip/hip_runtime.h>

#define BB 512
#define TT 2048
#define CH 64                 // steps per LDS chunk
#define NCH (TT/CH)           // 32 chunks

// ---------- fast math helpers ----------
__device__ __forceinline__ float fexp2(float x){ return __builtin_amdgcn_exp2f(x); }
__device__ __forceinline__ float frcp(float x){ return __builtin_amdgcn_rcpf(x); }

#define QB(v, ctrl) __int_as_float(__builtin_amdgcn_mov_dpp(__float_as_int(v), (ctrl), 0xF, 0xF, true))
#define RL(v, l)    __builtin_amdgcn_readlane((v), (l))

// ---------- fused producer/consumer ----------
// Block = 128 threads (2 waves) per batch element b.
//   wave 1 (producer): lane l computes gate l's input projection
//       sx[t][l] = kq_l * (b_ih[l]+b_hh[l] + Wih_row_l · x_t)     (lane 52: -log2e*fc_b)
//     into a double-buffered LDS chunk of CH steps. x loads are wave-uniform -> s_load;
//     no cross-lane ops anywhere. ~5x faster than the consumer.
//   wave 0 (consumer): the serial recurrence (unchanged 240cy/step chain); per step it
//     reads its seed with one ds_read_b32 (NOT convergent -> schedulable/prefetchable,
//     issued one 8-step group ahead). lane 4j+q = gate q of unit j; lane 52 computes
//     the fused FC output with the same instruction stream.
__global__ __launch_bounds__(128, 1) void k_fused(
    const float* __restrict__ x,
    const float* __restrict__ Wih,
    const float* __restrict__ Whh,
    const float* __restrict__ bih,
    const float* __restrict__ bhh,
    const float* __restrict__ fcw,
    const float* __restrict__ fcb,
    float* __restrict__ out)
{
  __shared__ float sxbuf[2][CH][64];   // 32 KB; col = gate id (bank 2-way max = free)

  const int tid  = threadIdx.x;
  const int wid  = tid >> 6;
  const int lane = tid & 63;
  const int b    = blockIdx.x;
  const float* xp = x + (size_t)b*(TT*13);

  // ---- producer state
  float wxp[13]; float biasp = 0.f;
  // ---- consumer state (top scope: must live across the chunk loop)
  float w[13];
  float kgm = 1.f, kga = 0.f, fcbias = 0.f;
  int   e = 0;
  float h = 0.f, c_ = 0.f;            // c_ carries -2*log2e*c
  float hb0=0,hb1=0,hb2=0,hb3=0,hb4=0,hb5=0,hb6=0,hb7=0,hb8=0,hb9=0,hb10=0,hb11=0,hb12=0;
  float p0=0,p1=0,p2=0,p3=0,p4=0,p5=0,p6=0,p7=0;
  float* op = out + (size_t)b*TT;
  bool first = true;

#define FILL(bi_, t0_) do {                                                   \
    _Pragma("unroll 2")                                                       \
    for (int tt=0; tt<CH; tt+=4){                                             \
      const float* rp = xp + (size_t)((t0_)+tt)*13;                           \
      float a0=biasp, a1=biasp, a2=biasp, a3=biasp;                           \
      _Pragma("unroll")                                                       \
      for (int k=0;k<13;++k){                                                 \
        a0 = fmaf(wxp[k], rp[k],    a0);                                      \
        a1 = fmaf(wxp[k], rp[13+k], a1);                                      \
        a2 = fmaf(wxp[k], rp[26+k], a2);                                      \
        a3 = fmaf(wxp[k], rp[39+k], a3);                                      \
      }                                                                       \
      sxbuf[bi_][tt+0][lane] = a0;                                            \
      sxbuf[bi_][tt+1][lane] = a1;                                            \
      sxbuf[bi_][tt+2][lane] = a2;                                            \
      sxbuf[bi_][tt+3][lane] = a3;                                            \
    }                                                                         \
  } while(0)

#define CAPTURE(gv_, u_) do {                                                 \
    if ((u_)==1) p0=(gv_); else if ((u_)==2) p1=(gv_);                        \
    else if ((u_)==3) p2=(gv_); else if ((u_)==4) p3=(gv_);                   \
    else if ((u_)==5) p4=(gv_); else if ((u_)==6) p5=(gv_);                   \
    else if ((u_)==7) p6=(gv_);                                               \
    else { p7=(gv_);                                                          \
      if (!first){                                                            \
        if (lane == 52){                                                      \
          float4* o4 = (float4*)op;                                           \
          o4[0] = make_float4(p0,p1,p2,p3);                                   \
          o4[1] = make_float4(p4,p5,p6,p7);                                   \
        }                                                                     \
        op += 8;                                                              \
      }                                                                       \
      first = false;                                                          \
    }                                                                         \
  } while(0)

#define STEP(xv_, u_) do {                                                    \
    float dA = fmaf(w[0], hb0, (xv_));                                        \
    dA = fmaf(w[1], hb1, dA);                                                 \
    dA = fmaf(w[2], hb2, dA);                                                 \
    dA = fmaf(w[3], hb3, dA);                                                 \
    dA = fmaf(w[4], hb4, dA);                                                 \
    float dB = w[5]*hb5;                                                      \
    dB = fmaf(w[6], hb6, dB);                                                 \
    dB = fmaf(w[7], hb7, dB);                                                 \
    dB = fmaf(w[8], hb8, dB);                                                 \
    float dC = w[9]*hb9;                                                      \
    dC = fmaf(w[10], hb10, dC);                                               \
    dC = fmaf(w[11], hb11, dC);                                               \
    dC = fmaf(w[12], hb12, dC);                                               \
    float s  = (dB + dC) + dA;                                                \
    float r  = frcp(1.f + fexp2(s));                                          \
    float g  = fmaf(kgm, r, kga);                                             \
    CAPTURE(g, u_);                                                           \
    float ggb = QB(g, 0xAA);                                                  \
    float gfb = QB(g, 0x55);                                                  \
    float gob = QB(g, 0xFF);                                                  \
    float go2 = gob + gob;                                                    \
    c_ = fmaf(gfb, c_, g*ggb);                                                \
    float r2 = frcp(1.f + fexp2(c_));                                         \
    h = fmaf(go2, r2, -gob);                                                  \
    int hv_ = __float_as_int(h);                                              \
    hb0  = __int_as_float(RL(hv_, 0));                                        \
    hb1  = __int_as_float(RL(hv_, 4));                                        \
    hb2  = __int_as_float(RL(hv_, 8));                                        \
    hb3  = __int_as_float(RL(hv_, 12));                                       \
    hb4  = __int_as_float(RL(hv_, 16));                                       \
    hb5  = __int_as_float(RL(hv_, 20));                                       \
    hb6  = __int_as_float(RL(hv_, 24));                                       \
    hb7  = __int_as_float(RL(hv_, 28));                                       \
    hb8  = __int_as_float(RL(hv_, 32));                                       \
    hb9  = __int_as_float(RL(hv_, 36));                                       \
    hb10 = __int_as_float(RL(hv_, 40));                                       \
    hb11 = __int_as_float(RL(hv_, 44));                                       \
    hb12 = __int_as_float(RL(hv_, 48));                                       \
  } while(0)

// consume one CH-step chunk from buffer bi_, with one-group-ahead ds_read prefetch
#define CONSUME(bi_) do {                                                     \
    float rc[8], rn[8];                                                       \
    _Pragma("unroll")                                                         \
    for (int u=0;u<8;++u) rc[u] = sxbuf[bi_][u][e];                           \
    _Pragma("unroll 2")                                                       \
    for (int g=0; g<CH/8; ++g){                                               \
      const int tn = (g < CH/8-1) ? ((g+1)<<3) : 0;  /* tail: dummy in-bounds */\
      _Pragma("unroll")                                                       \
      for (int u=0;u<8;++u) rn[u] = sxbuf[bi_][tn+u][e];                      \
      STEP(rc[0],0); STEP(rc[1],1); STEP(rc[2],2); STEP(rc[3],3);             \
      STEP(rc[4],4); STEP(rc[5],5); STEP(rc[6],6); STEP(rc[7],7);             \
      _Pragma("unroll")                                                       \
      for (int u=0;u<8;++u) rc[u] = rn[u];                                    \
    }                                                                         \
  } while(0)

  if (wid == 1){
    // -------- producer setup: gate = lane --------
    const int  l     = lane;
    const bool fcrow = (l == 52);
    const int  row   = (l < 52) ? l : 0;
    const float kql  = (l >= 26 && l < 39) ? -2.8853900817779268f : -1.4426950408889634f;
    const float kx   = fcrow ? 0.f : kql;
    #pragma unroll
    for (int k=0;k<13;k++) wxp[k] = Wih[row*13+k]*kx;
    biasp = fcrow ? (-1.4426950408889634f * fcb[0])
                  : ((l < 52) ? (bih[row]+bhh[row])*kql : 0.f);
    FILL(0, 0);
  } else {
    // -------- consumer setup: lane 4j+q --------
    const int  q   = lane & 3;
    const int  j   = lane >> 2;
    const int  jc  = (j < 13) ? j : 12;
    const bool fcl = (lane == 52);
    e = fcl ? 52 : q*13 + jc;
    const float kq = (q==2) ? -2.8853900817779268f : -1.4426950408889634f;
    kgm = (q==2) ? -5.7707801635558536f : 1.f;
    kga = (q==2) ?  2.8853900817779268f : 0.f;
    fcbias = -1.4426950408889634f * fcb[0];
    const float* wsrc = fcl ? fcw : (Whh + (size_t)e*13);
    #pragma unroll
    for (int k=0;k<13;k++) w[k] = wsrc[k]*kq;
  }
  __syncthreads();                                  // chunk 0 ready

  for (int c=0; c<NCH-1; ++c){
    if (wid == 1){ FILL((c+1)&1, (c+1)*CH); }
    else         { CONSUME(c&1); }
    __syncthreads();                                // chunk c+1 ready; chunk c-? freed
  }

  if (wid == 0){
    CONSUME((NCH-1)&1);                             // chunk 31

    // epilogue: out[2047] = sigmoid(fc_b + fc_w·h_2047); lane 52 stores p0..p6 + r
    float s = fcbias;
    s = fmaf(w[0],  hb0,  s);
    s = fmaf(w[1],  hb1,  s);
    s = fmaf(w[2],  hb2,  s);
    s = fmaf(w[3],  hb3,  s);
    s = fmaf(w[4],  hb4,  s);
    s = fmaf(w[5],  hb5,  s);
    s = fmaf(w[6],  hb6,  s);
    s = fmaf(w[7],  hb7,  s);
    s = fmaf(w[8],  hb8,  s);
    s = fmaf(w[9],  hb9,  s);
    s = fmaf(w[10], hb10, s);
    s = fmaf(w[11], hb11, s);
    s = fmaf(w[12], hb12, s);
    float r = frcp(1.f + fexp2(s));
    if (lane == 52){
      float4* o4 = (float4*)op;                     // op == out + b*TT + 2040 here
      o4[0] = make_float4(p0,p1,p2,p3);
      o4[1] = make_float4(p4,p5,p6,r);
    }
  }

#undef CONSUME
#undef STEP
#undef CAPTURE
#undef FILL
}

extern "C" void kernel_launch(void* const* d_in, const int* in_sizes, int n_in,
                              void* d_out, int out_size, void* d_ws, size_t ws_size,
                              hipStream_t stream)
{
  const float* x   = (const float*)d_in[0];
  const float* Wih = (const float*)d_in[1];
  const float* Whh = (const float*)d_in[2];
  const float* bih = (const float*)d_in[3];
  const float* bhh = (const float*)d_in[4];
  const float* fcw = (const float*)d_in[5];
  const float* fcb = (const float*)d_in[6];
  float* out = (float*)d_out;

  (void)d_ws; (void)ws_size;   // fully fused: no workspace
  k_fused<<<dim3(BB), dim3(128), 0, stream>>>(x, Wih, Whh, bih, bhh, fcw, fcb, out);
}

// Round 3
// 353.206 us; speedup vs baseline: 1.0783x; 1.0346x over previous
//
#include <hip/hip_runtime.h>

#define BB 512
#define TT 2048
#define CH 64                 // steps per LDS chunk
#define NCH (TT/CH)           // 32 chunks

// ---------- fast math helpers ----------
__device__ __forceinline__ float fexp2(float x){ return __builtin_amdgcn_exp2f(x); }
__device__ __forceinline__ float frcp(float x){ return __builtin_amdgcn_rcpf(x); }

#define QB(v, ctrl) __int_as_float(__builtin_amdgcn_mov_dpp(__float_as_int(v), (ctrl), 0xF, 0xF, true))
#define RL(v, l)    __builtin_amdgcn_readlane((v), (l))

// ---------- fused producer/consumer, round 3 ----------
// Block = 128 threads (2 waves) per batch element b.
//   wave 1 (producer): per chunk of CH steps,
//     (a) loads the chunk's raw x (CH*13 floats) with 13 COALESCED per-lane
//         global_load_dword (lane + 64*i), issued one chunk ahead (vmcnt covers HBM);
//     (b) stages it flat into LDS xraw (double-buffered);
//     (c) computes sx[t][gate] = kq*(bias + Wih_row·x_t) via broadcast ds_read_b32
//         (all lanes read the same xraw[t*13+k] -> conflict-free broadcast) + FMA,
//         writing sxbuf[t][lane].  ~4K cy/chunk << consumer's 15.4K cy/chunk.
//     Round-2 failure mode (uniform-address x loads scalarized to s_load, SMEM-depth
//     serialized, ~27K cy/chunk) is gone: every global access is per-lane vector.
//   wave 0 (consumer): unchanged 240cy/step serial recurrence; per step one
//     ds_read_b32 seed, prefetched one 8-step group ahead. lane 4j+q = gate q of
//     unit j; lane 52 computes the fused FC output in the same instruction stream.
__global__ __launch_bounds__(128, 1) void k_fused2(
    const float* __restrict__ x,
    const float* __restrict__ Wih,
    const float* __restrict__ Whh,
    const float* __restrict__ bih,
    const float* __restrict__ bhh,
    const float* __restrict__ fcw,
    const float* __restrict__ fcb,
    float* __restrict__ out)
{
  __shared__ float sxbuf[2][CH][64];   // 32 KB; col = gate id (2-way bank = free)
  __shared__ float xraw[2][CH*13];     // 6.5 KB raw-x staging (producer-private)

  const int tid  = threadIdx.x;
  const int wid  = tid >> 6;
  const int lane = tid & 63;
  const int b    = blockIdx.x;
  const float* xp = x + (size_t)b*(TT*13);

  // ---- producer state
  float wxp[13]; float biasp = 0.f; float xr[13];
  // ---- consumer state (top scope: lives across the chunk loop)
  float w[13];
  float kgm = 1.f, kga = 0.f, fcbias = 0.f;
  int   e = 0;
  float h = 0.f, c_ = 0.f;            // c_ carries -2*log2e*c
  float hb0=0,hb1=0,hb2=0,hb3=0,hb4=0,hb5=0,hb6=0,hb7=0,hb8=0,hb9=0,hb10=0,hb11=0,hb12=0;
  float p0=0,p1=0,p2=0,p3=0,p4=0,p5=0,p6=0,p7=0;
  float* op = out + (size_t)b*TT;
  bool first = true;

// coalesced chunk load: 13 per-lane dwords (lane + 64*i), contiguous 3.3 KB
#define PLOAD(c_) do {                                                        \
    const float* srcp_ = xp + (size_t)(c_)*(CH*13);                           \
    _Pragma("unroll")                                                         \
    for (int i=0;i<13;++i) xr[i] = srcp_[lane + (i<<6)];                      \
  } while(0)

// stage regs -> LDS flat (straight copy; compiler inserts the vmcnt wait)
#define PSTAGE(bi_) do {                                                      \
    _Pragma("unroll")                                                         \
    for (int i=0;i<13;++i) xraw[bi_][lane + (i<<6)] = xr[i];                  \
  } while(0)

// compute one chunk of sx from staged raw x (broadcast reads, per-lane FMAs)
#define PFILL(bi_) do {                                                       \
    _Pragma("unroll 4")                                                       \
    for (int tt=0; tt<CH; ++tt){                                              \
      float a_ = biasp;                                                       \
      _Pragma("unroll")                                                       \
      for (int k=0;k<13;++k)                                                  \
        a_ = fmaf(wxp[k], xraw[bi_][tt*13+k], a_);                            \
      sxbuf[bi_][tt][lane] = a_;                                              \
    }                                                                         \
  } while(0)

#define CAPTURE(gv_, u_) do {                                                 \
    if ((u_)==1) p0=(gv_); else if ((u_)==2) p1=(gv_);                        \
    else if ((u_)==3) p2=(gv_); else if ((u_)==4) p3=(gv_);                   \
    else if ((u_)==5) p4=(gv_); else if ((u_)==6) p5=(gv_);                   \
    else if ((u_)==7) p6=(gv_);                                               \
    else { p7=(gv_);                                                          \
      if (!first){                                                            \
        if (lane == 52){                                                      \
          float4* o4 = (float4*)op;                                           \
          o4[0] = make_float4(p0,p1,p2,p3);                                   \
          o4[1] = make_float4(p4,p5,p6,p7);                                   \
        }                                                                     \
        op += 8;                                                              \
      }                                                                       \
      first = false;                                                          \
    }                                                                         \
  } while(0)

#define STEP(xv_, u_) do {                                                    \
    float dA = fmaf(w[0], hb0, (xv_));                                        \
    dA = fmaf(w[1], hb1, dA);                                                 \
    dA = fmaf(w[2], hb2, dA);                                                 \
    dA = fmaf(w[3], hb3, dA);                                                 \
    dA = fmaf(w[4], hb4, dA);                                                 \
    float dB = w[5]*hb5;                                                      \
    dB = fmaf(w[6], hb6, dB);                                                 \
    dB = fmaf(w[7], hb7, dB);                                                 \
    dB = fmaf(w[8], hb8, dB);                                                 \
    float dC = w[9]*hb9;                                                      \
    dC = fmaf(w[10], hb10, dC);                                               \
    dC = fmaf(w[11], hb11, dC);                                               \
    dC = fmaf(w[12], hb12, dC);                                               \
    float s  = (dB + dC) + dA;                                                \
    float r  = frcp(1.f + fexp2(s));                                          \
    float g  = fmaf(kgm, r, kga);                                             \
    CAPTURE(g, u_);                                                           \
    float ggb = QB(g, 0xAA);                                                  \
    float gfb = QB(g, 0x55);                                                  \
    float gob = QB(g, 0xFF);                                                  \
    float go2 = gob + gob;                                                    \
    c_ = fmaf(gfb, c_, g*ggb);                                                \
    float r2 = frcp(1.f + fexp2(c_));                                         \
    h = fmaf(go2, r2, -gob);                                                  \
    int hv_ = __float_as_int(h);                                              \
    hb0  = __int_as_float(RL(hv_, 0));                                        \
    hb1  = __int_as_float(RL(hv_, 4));                                        \
    hb2  = __int_as_float(RL(hv_, 8));                                        \
    hb3  = __int_as_float(RL(hv_, 12));                                       \
    hb4  = __int_as_float(RL(hv_, 16));                                       \
    hb5  = __int_as_float(RL(hv_, 20));                                       \
    hb6  = __int_as_float(RL(hv_, 24));                                       \
    hb7  = __int_as_float(RL(hv_, 28));                                       \
    hb8  = __int_as_float(RL(hv_, 32));                                       \
    hb9  = __int_as_float(RL(hv_, 36));                                       \
    hb10 = __int_as_float(RL(hv_, 40));                                       \
    hb11 = __int_as_float(RL(hv_, 44));                                       \
    hb12 = __int_as_float(RL(hv_, 48));                                       \
  } while(0)

// consume one CH-step chunk from buffer bi_, with one-group-ahead ds_read prefetch
#define CONSUME(bi_) do {                                                     \
    float rc[8], rn[8];                                                       \
    _Pragma("unroll")                                                         \
    for (int u=0;u<8;++u) rc[u] = sxbuf[bi_][u][e];                           \
    _Pragma("unroll 2")                                                       \
    for (int g=0; g<CH/8; ++g){                                               \
      const int tn = (g < CH/8-1) ? ((g+1)<<3) : 0;  /* tail: dummy in-bounds */\
      _Pragma("unroll")                                                       \
      for (int u=0;u<8;++u) rn[u] = sxbuf[bi_][tn+u][e];                      \
      STEP(rc[0],0); STEP(rc[1],1); STEP(rc[2],2); STEP(rc[3],3);             \
      STEP(rc[4],4); STEP(rc[5],5); STEP(rc[6],6); STEP(rc[7],7);             \
      _Pragma("unroll")                                                       \
      for (int u=0;u<8;++u) rc[u] = rn[u];                                    \
    }                                                                         \
  } while(0)

  if (wid == 1){
    // -------- producer setup: gate = lane --------
    const int  l     = lane;
    const bool fcrow = (l == 52);
    const int  row   = (l < 52) ? l : 0;
    const float kql  = (l >= 26 && l < 39) ? -2.8853900817779268f : -1.4426950408889634f;
    const float kx   = fcrow ? 0.f : kql;
    #pragma unroll
    for (int k=0;k<13;k++) wxp[k] = Wih[row*13+k]*kx;
    biasp = fcrow ? (-1.4426950408889634f * fcb[0])
                  : ((l < 52) ? (bih[row]+bhh[row])*kql : 0.f);
    PLOAD(0);                 // chunk 0 raw x
    PSTAGE(0);                // -> xraw[0]
    PLOAD(1);                 // prefetch chunk 1 (in flight during PFILL)
    PFILL(0);                 // sx chunk 0
  } else {
    // -------- consumer setup: lane 4j+q --------
    const int  q   = lane & 3;
    const int  j   = lane >> 2;
    const int  jc  = (j < 13) ? j : 12;
    const bool fcl = (lane == 52);
    e = fcl ? 52 : q*13 + jc;
    const float kq = (q==2) ? -2.8853900817779268f : -1.4426950408889634f;
    kgm = (q==2) ? -5.7707801635558536f : 1.f;
    kga = (q==2) ?  2.8853900817779268f : 0.f;
    fcbias = -1.4426950408889634f * fcb[0];
    const float* wsrc = fcl ? fcw : (Whh + (size_t)e*13);
    #pragma unroll
    for (int k=0;k<13;k++) w[k] = wsrc[k]*kq;
  }
  __syncthreads();                                  // sx chunk 0 ready

  for (int c=0; c<NCH-1; ++c){
    if (wid == 1){
      const int bi = (c+1)&1;
      PSTAGE(bi);                                   // xr holds chunk c+1 (vmcnt wait auto)
      const int c2 = (c+2 < NCH) ? (c+2) : (NCH-1); // prefetch chunk c+2 (clamped)
      PLOAD(c2);
      PFILL(bi);                                    // sx chunk c+1
    } else {
      CONSUME(c&1);
    }
    __syncthreads();                                // sx chunk c+1 ready
  }

  if (wid == 0){
    CONSUME((NCH-1)&1);                             // chunk 31

    // epilogue: out[2047] = sigmoid(fc_b + fc_w·h_2047); lane 52 stores p0..p6 + r
    float s = fcbias;
    s = fmaf(w[0],  hb0,  s);
    s = fmaf(w[1],  hb1,  s);
    s = fmaf(w[2],  hb2,  s);
    s = fmaf(w[3],  hb3,  s);
    s = fmaf(w[4],  hb4,  s);
    s = fmaf(w[5],  hb5,  s);
    s = fmaf(w[6],  hb6,  s);
    s = fmaf(w[7],  hb7,  s);
    s = fmaf(w[8],  hb8,  s);
    s = fmaf(w[9],  hb9,  s);
    s = fmaf(w[10], hb10, s);
    s = fmaf(w[11], hb11, s);
    s = fmaf(w[12], hb12, s);
    float r = frcp(1.f + fexp2(s));
    if (lane == 52){
      float4* o4 = (float4*)op;                     // op == out + b*TT + 2040 here
      o4[0] = make_float4(p0,p1,p2,p3);
      o4[1] = make_float4(p4,p5,p6,r);
    }
  }

#undef CONSUME
#undef STEP
#undef CAPTURE
#undef PFILL
#undef PSTAGE
#undef PLOAD
}

extern "C" void kernel_launch(void* const* d_in, const int* in_sizes, int n_in,
                              void* d_out, int out_size, void* d_ws, size_t ws_size,
                              hipStream_t stream)
{
  const float* x   = (const float*)d_in[0];
  const float* Wih = (const float*)d_in[1];
  const float* Whh = (const float*)d_in[2];
  const float* bih = (const float*)d_in[3];
  const float* bhh = (const float*)d_in[4];
  const float* fcw = (const float*)d_in[5];
  const float* fcb = (const float*)d_in[6];
  float* out = (float*)d_out;

  (void)d_ws; (void)ws_size;   // fully fused: no workspace
  k_fused2<<<dim3(BB), dim3(128), 0, stream>>>(x, Wih, Whh, bih, bhh, fcw, fcb, out);
}

// Round 4
// 352.826 us; speedup vs baseline: 1.0795x; 1.0011x over previous
//
#include <hip/hip_runtime.h>

#define BB 512
#define TT 2048
#define CH 64                 // steps per LDS chunk
#define NCH (TT/CH)           // 32 chunks

// ---------- fast math helpers ----------
__device__ __forceinline__ float fexp2(float x){ return __builtin_amdgcn_exp2f(x); }
__device__ __forceinline__ float frcp(float x){ return __builtin_amdgcn_rcpf(x); }

#define QB(v, ctrl) __int_as_float(__builtin_amdgcn_mov_dpp(__float_as_int(v), (ctrl), 0xF, 0xF, true))
#define RL(v, l)    __builtin_amdgcn_readlane((v), (l))

// ---------- fused producer/consumer, round 4 ----------
// Block = 128 threads (2 waves) per batch element b.
//   wave 1 (producer): ZERO LDS reads. The chunk's raw x (832 floats) lives in
//     13 per-lane registers (flat layout: reg i, lane l  <->  x[chunk*832 + i*64 + l],
//     loaded with 13 coalesced global_load_dword). Element f = tt*13+k is broadcast
//     with v_readlane(xr[f>>6], f&63) -- both indices compile-time after full unroll.
//     Readlane is short-latency, fully pipelined, no wait counters: per chunk
//     ~64*(13 RL + 13 FMA + 1 ds_write) ~= 4-6K cy << consumer's 15.4K budget.
//     (Round-3 failure: 832 dependent broadcast ds_read->fma pairs exposed LDS
//     latency via in-order lgkmcnt waits -> ~21K cy/chunk. Gone.)
//     Register double-buffer A/B + 13-mov rotate avoids dual code instantiation.
//   wave 0 (consumer): unchanged 240cy/step serial recurrence; per step one
//     ds_read_b32 seed, prefetched one 8-step group ahead. lane 4j+q = gate q of
//     unit j; lane 52 computes the fused FC output in the same instruction stream.
__global__ __launch_bounds__(128, 1) void k_fused3(
    const float* __restrict__ x,
    const float* __restrict__ Wih,
    const float* __restrict__ Whh,
    const float* __restrict__ bih,
    const float* __restrict__ bhh,
    const float* __restrict__ fcw,
    const float* __restrict__ fcb,
    float* __restrict__ out)
{
  __shared__ float sxbuf[2][CH][64];   // 32 KB; col = gate id (2-way bank = free)

  const int tid  = threadIdx.x;
  const int wid  = tid >> 6;
  const int lane = tid & 63;
  const int b    = blockIdx.x;
  const float* xp = x + (size_t)b*(TT*13);

  // ---- producer state
  float wxp[13]; float biasp = 0.f;
  float xrA[13], xrB[13];
  // ---- consumer state (top scope: lives across the chunk loop)
  float w[13];
  float kgm = 1.f, kga = 0.f, fcbias = 0.f;
  int   e = 0;
  float h = 0.f, c_ = 0.f;            // c_ carries -2*log2e*c
  float hb0=0,hb1=0,hb2=0,hb3=0,hb4=0,hb5=0,hb6=0,hb7=0,hb8=0,hb9=0,hb10=0,hb11=0,hb12=0;
  float p0=0,p1=0,p2=0,p3=0,p4=0,p5=0,p6=0,p7=0;
  float* op = out + (size_t)b*TT;
  bool first = true;

// coalesced chunk load into register set XR: 13 per-lane dwords (lane + 64*i)
#define PLOADR(c_, XR) do {                                                   \
    const float* srcp_ = xp + (size_t)(c_)*(CH*13);                           \
    _Pragma("unroll")                                                         \
    for (int i=0;i<13;++i) XR[i] = srcp_[lane + (i<<6)];                      \
  } while(0)

// rotate register double-buffer: A <- B (13 movs; vmcnt wait on B auto-inserted)
#define PROT() do {                                                           \
    _Pragma("unroll")                                                         \
    for (int i=0;i<13;++i) xrA[i] = xrB[i];                                   \
  } while(0)

// compute one chunk of sx from register set xrA via readlane broadcast (no LDS reads)
#define PFILLR(bi_) do {                                                      \
    _Pragma("unroll")                                                         \
    for (int tt=0; tt<CH; ++tt){                                              \
      float a_ = biasp;                                                       \
      _Pragma("unroll")                                                       \
      for (int k=0;k<13;++k){                                                 \
        const int f_ = tt*13 + k;                                             \
        a_ = fmaf(wxp[k],                                                     \
                  __int_as_float(RL(__float_as_int(xrA[f_>>6]), f_&63)), a_); \
      }                                                                       \
      sxbuf[bi_][tt][lane] = a_;                                              \
    }                                                                         \
  } while(0)

#define CAPTURE(gv_, u_) do {                                                 \
    if ((u_)==1) p0=(gv_); else if ((u_)==2) p1=(gv_);                        \
    else if ((u_)==3) p2=(gv_); else if ((u_)==4) p3=(gv_);                   \
    else if ((u_)==5) p4=(gv_); else if ((u_)==6) p5=(gv_);                   \
    else if ((u_)==7) p6=(gv_);                                               \
    else { p7=(gv_);                                                          \
      if (!first){                                                            \
        if (lane == 52){                                                      \
          float4* o4 = (float4*)op;                                           \
          o4[0] = make_float4(p0,p1,p2,p3);                                   \
          o4[1] = make_float4(p4,p5,p6,p7);                                   \
        }                                                                     \
        op += 8;                                                              \
      }                                                                       \
      first = false;                                                          \
    }                                                                         \
  } while(0)

#define STEP(xv_, u_) do {                                                    \
    float dA = fmaf(w[0], hb0, (xv_));                                        \
    dA = fmaf(w[1], hb1, dA);                                                 \
    dA = fmaf(w[2], hb2, dA);                                                 \
    dA = fmaf(w[3], hb3, dA);                                                 \
    dA = fmaf(w[4], hb4, dA);                                                 \
    float dB = w[5]*hb5;                                                      \
    dB = fmaf(w[6], hb6, dB);                                                 \
    dB = fmaf(w[7], hb7, dB);                                                 \
    dB = fmaf(w[8], hb8, dB);                                                 \
    float dC = w[9]*hb9;                                                      \
    dC = fmaf(w[10], hb10, dC);                                               \
    dC = fmaf(w[11], hb11, dC);                                               \
    dC = fmaf(w[12], hb12, dC);                                               \
    float s  = (dB + dC) + dA;                                                \
    float r  = frcp(1.f + fexp2(s));                                          \
    float g  = fmaf(kgm, r, kga);                                             \
    CAPTURE(g, u_);                                                           \
    float ggb = QB(g, 0xAA);                                                  \
    float gfb = QB(g, 0x55);                                                  \
    float gob = QB(g, 0xFF);                                                  \
    float go2 = gob + gob;                                                    \
    c_ = fmaf(gfb, c_, g*ggb);                                                \
    float r2 = frcp(1.f + fexp2(c_));                                         \
    h = fmaf(go2, r2, -gob);                                                  \
    int hv_ = __float_as_int(h);                                              \
    hb0  = __int_as_float(RL(hv_, 0));                                        \
    hb1  = __int_as_float(RL(hv_, 4));                                        \
    hb2  = __int_as_float(RL(hv_, 8));                                        \
    hb3  = __int_as_float(RL(hv_, 12));                                       \
    hb4  = __int_as_float(RL(hv_, 16));                                       \
    hb5  = __int_as_float(RL(hv_, 20));                                       \
    hb6  = __int_as_float(RL(hv_, 24));                                       \
    hb7  = __int_as_float(RL(hv_, 28));                                       \
    hb8  = __int_as_float(RL(hv_, 32));                                       \
    hb9  = __int_as_float(RL(hv_, 36));                                       \
    hb10 = __int_as_float(RL(hv_, 40));                                       \
    hb11 = __int_as_float(RL(hv_, 44));                                       \
    hb12 = __int_as_float(RL(hv_, 48));                                       \
  } while(0)

// consume one CH-step chunk from buffer bi_, with one-group-ahead ds_read prefetch
#define CONSUME(bi_) do {                                                     \
    float rc[8], rn[8];                                                       \
    _Pragma("unroll")                                                         \
    for (int u=0;u<8;++u) rc[u] = sxbuf[bi_][u][e];                           \
    _Pragma("unroll 2")                                                       \
    for (int g=0; g<CH/8; ++g){                                               \
      const int tn = (g < CH/8-1) ? ((g+1)<<3) : 0;  /* tail: dummy in-bounds */\
      _Pragma("unroll")                                                       \
      for (int u=0;u<8;++u) rn[u] = sxbuf[bi_][tn+u][e];                      \
      STEP(rc[0],0); STEP(rc[1],1); STEP(rc[2],2); STEP(rc[3],3);             \
      STEP(rc[4],4); STEP(rc[5],5); STEP(rc[6],6); STEP(rc[7],7);             \
      _Pragma("unroll")                                                       \
      for (int u=0;u<8;++u) rc[u] = rn[u];                                    \
    }                                                                         \
  } while(0)

  if (wid == 1){
    // -------- producer setup: gate = lane --------
    const int  l     = lane;
    const bool fcrow = (l == 52);
    const int  row   = (l < 52) ? l : 0;
    const float kql  = (l >= 26 && l < 39) ? -2.8853900817779268f : -1.4426950408889634f;
    const float kx   = fcrow ? 0.f : kql;
    #pragma unroll
    for (int k=0;k<13;k++) wxp[k] = Wih[row*13+k]*kx;
    biasp = fcrow ? (-1.4426950408889634f * fcb[0])
                  : ((l < 52) ? (bih[row]+bhh[row])*kql : 0.f);
    PLOADR(0, xrA);           // chunk 0 raw x -> A
    PLOADR(1, xrB);           // chunk 1 raw x -> B
    PFILLR(0);                // sx chunk 0 (from A)
    PROT();                   // A <- B (chunk 1)
    PLOADR(2, xrB);           // prefetch chunk 2 -> B
  } else {
    // -------- consumer setup: lane 4j+q --------
    const int  q   = lane & 3;
    const int  j   = lane >> 2;
    const int  jc  = (j < 13) ? j : 12;
    const bool fcl = (lane == 52);
    e = fcl ? 52 : q*13 + jc;
    const float kq = (q==2) ? -2.8853900817779268f : -1.4426950408889634f;
    kgm = (q==2) ? -5.7707801635558536f : 1.f;
    kga = (q==2) ?  2.8853900817779268f : 0.f;
    fcbias = -1.4426950408889634f * fcb[0];
    const float* wsrc = fcl ? fcw : (Whh + (size_t)e*13);
    #pragma unroll
    for (int k=0;k<13;k++) w[k] = wsrc[k]*kq;
  }
  __syncthreads();                                  // sx chunk 0 ready

  for (int c=0; c<NCH-1; ++c){
    if (wid == 1){
      PFILLR((c+1)&1);                              // sx chunk c+1 (from A)
      PROT();                                       // A <- B (chunk c+2)
      const int c3 = (c+3 < NCH) ? (c+3) : (NCH-1); // prefetch chunk c+3 (clamped)
      PLOADR(c3, xrB);
    } else {
      CONSUME(c&1);                                 // chunk c
    }
    __syncthreads();                                // sx chunk c+1 ready
  }

  if (wid == 0){
    CONSUME((NCH-1)&1);                             // chunk 31

    // epilogue: out[2047] = sigmoid(fc_b + fc_w·h_2047); lane 52 stores p0..p6 + r
    float s = fcbias;
    s = fmaf(w[0],  hb0,  s);
    s = fmaf(w[1],  hb1,  s);
    s = fmaf(w[2],  hb2,  s);
    s = fmaf(w[3],  hb3,  s);
    s = fmaf(w[4],  hb4,  s);
    s = fmaf(w[5],  hb5,  s);
    s = fmaf(w[6],  hb6,  s);
    s = fmaf(w[7],  hb7,  s);
    s = fmaf(w[8],  hb8,  s);
    s = fmaf(w[9],  hb9,  s);
    s = fmaf(w[10], hb10, s);
    s = fmaf(w[11], hb11, s);
    s = fmaf(w[12], hb12, s);
    float r = frcp(1.f + fexp2(s));
    if (lane == 52){
      float4* o4 = (float4*)op;                     // op == out + b*TT + 2040 here
      o4[0] = make_float4(p0,p1,p2,p3);
      o4[1] = make_float4(p4,p5,p6,r);
    }
  }

#undef CONSUME
#undef STEP
#undef CAPTURE
#undef PFILLR
#undef PROT
#undef PLOADR
}

extern "C" void kernel_launch(void* const* d_in, const int* in_sizes, int n_in,
                              void* d_out, int out_size, void* d_ws, size_t ws_size,
                              hipStream_t stream)
{
  const float* x   = (const float*)d_in[0];
  const float* Wih = (const float*)d_in[1];
  const float* Whh = (const float*)d_in[2];
  const float* bih = (const float*)d_in[3];
  const float* bhh = (const float*)d_in[4];
  const float* fcw = (const float*)d_in[5];
  const float* fcb = (const float*)d_in[6];
  float* out = (float*)d_out;

  (void)d_ws; (void)ws_size;   // fully fused: no workspace
  k_fused3<<<dim3(BB), dim3(128), 0, stream>>>(x, Wih, Whh, bih, bhh, fcw, fcb, out);
}